// Round 6
// baseline (1822.961 us; speedup 1.0000x reference)
//
#include <hip/hip_runtime.h>
#include <cstdint>
#include <math.h>

// Locked-in: f32 in/out; output layout [4096*144 samples][4096 logP]; compare
// bf16-quantized; threshold 2.03 = 2% of max|logP|~101.5.
// Model (validated r2-r5): sampling decisions are arithmetic-robust (r2/r3/r4
// used three different arithmetics with one stream -> bit-identical 4.5);
// absmax is determined by the PRNG stream alone. Streams tested:
//   r2-4: original split + original bits        -> 4.5 (decorrelated)
//   r5:   partitionable split + low-word (o1)   -> 4.0 (decorrelated)
// THIS ROUND: JAX partitionable random_bits for bit_width<=32 returns
// bits1 ^ bits2 (XOR-fold of both threefry output words), not the low word
// (jax/_src/prng.py _threefry_random_bits_partitionable). Split unchanged:
// key_t = (o0, o1) of threefry((0,42), (0,t)).
// Forward pass kept from r4/r5 (np-f32 emulation, correctly-rounded f32
// transcendentals) — not load-bearing per the robustness evidence, simplify
// only after green.

#define NSAMP 4096
#define NSTEP 144
#define HID 64

// ---- JAX threefry2x32 (20 rounds, key-inject every 4) ----
__device__ __forceinline__ void threefry2x32(uint32_t k0, uint32_t k1,
                                             uint32_t x0, uint32_t x1,
                                             uint32_t& o0, uint32_t& o1) {
  const uint32_t ks0 = k0, ks1 = k1, ks2 = k0 ^ k1 ^ 0x1BD11BDAu;
  x0 += ks0; x1 += ks1;
#define TF_ROUND(d) { x0 += x1; x1 = (x1 << (d)) | (x1 >> (32 - (d))); x1 ^= x0; }
  TF_ROUND(13) TF_ROUND(15) TF_ROUND(26) TF_ROUND(6)
  x0 += ks1; x1 += ks2 + 1u;
  TF_ROUND(17) TF_ROUND(29) TF_ROUND(16) TF_ROUND(24)
  x0 += ks2; x1 += ks0 + 2u;
  TF_ROUND(13) TF_ROUND(15) TF_ROUND(26) TF_ROUND(6)
  x0 += ks0; x1 += ks1 + 3u;
  TF_ROUND(17) TF_ROUND(29) TF_ROUND(16) TF_ROUND(24)
  x0 += ks1; x1 += ks2 + 4u;
  TF_ROUND(13) TF_ROUND(15) TF_ROUND(26) TF_ROUND(6)
  x0 += ks2; x1 += ks0 + 5u;
#undef TF_ROUND
  o0 = x0; o1 = x1;
}

// correctly-rounded f32 transcendentals (f64 eval, single final rounding)
__device__ __forceinline__ float cr_expf(float x) { return (float)exp((double)x); }
__device__ __forceinline__ float cr_logf(float x) { return (float)log((double)x); }
__device__ __forceinline__ float cr_tanhf(float x) { return (float)tanh((double)x); }

__global__ __launch_bounds__(64, 1) void vmc_kernel(
    const float* __restrict__ W, const float* __restrict__ U,
    const float* __restrict__ B, const float* __restrict__ Wd,
    const float* __restrict__ Bd, float* __restrict__ out) {
#pragma clang fp contract(off)
  const int s = blockIdx.x;     // sample chain
  const int j = threadIdx.x;    // hidden unit

  __shared__ __align__(16) float hsh[HID];
  __shared__ __align__(16) float wdsh[2 * HID];   // Wd row-major (64,2)
  __shared__ uint2 kkeys[NSTEP];
  __shared__ float gsh[2 * NSTEP];

  // --- per-step keys, partitionable split: key_t = threefry((0,42),(0,t)),
  // new key = (o0, o1) stacked ---
  for (int t = j; t < NSTEP; t += HID) {
    uint32_t o0, o1;
    threefry2x32(0u, 42u, 0u, (uint32_t)t, o0, o1);
    kkeys[t].x = o0; kkeys[t].y = o1;
  }
  for (int idx = j; idx < 2 * HID; idx += HID) wdsh[idx] = Wd[idx];
  __syncthreads();

  // --- per-step gumbels, partitionable random_bits (bit_width=32):
  // flat counter i = 2s+c over shape (4096,2); bits = o0 ^ o1 (XOR-fold) ---
  for (int idx = j; idx < 2 * NSTEP; idx += HID) {
    const uint2 kt = kkeys[idx >> 1];
    const uint32_t i = 2u * (uint32_t)s + (uint32_t)(idx & 1);
    uint32_t o0, o1;
    threefry2x32(kt.x, kt.y, 0u, i, o0, o1);
    const uint32_t bits = o0 ^ o1;             // <-- the round-6 change
    union { uint32_t u; float fl; } c; c.u = (bits >> 9) | 0x3F800000u;
    float uf = c.fl - 1.0f;                    // exact
    uf = fmaxf(uf, 1.17549435e-38f);           // jax uniform minval=tiny
    const float inner = cr_logf(uf);           // np.log(u) rounded to f32
    gsh[idx] = -cr_logf(-inner);               // -np.log(-inner)
  }

  // --- register-resident U columns for unit j (f32, exact input data) ---
  float Uz[HID], Ur[HID], Un[HID];
#pragma unroll
  for (int i = 0; i < HID; ++i) {
    Uz[i] = U[i*192 + j];
    Ur[i] = U[i*192 + 64 + j];
    Un[i] = U[i*192 + 128 + j];
  }
  const float b1z = B[192 + j], b1r = B[256 + j], b1n = B[320 + j];
  const float b0z = B[j],       b0r = B[64 + j],  b0n = B[128 + j];
  // xm rows for s_prev = 0/1 (one-hot sgemm row is exact; b == 0 anyway)
  const float xz0 = W[j]       + b0z, xz1 = W[192 + j] + b0z;
  const float xr0 = W[64 + j]  + b0r, xr1 = W[256 + j] + b0r;
  const float xn0 = W[128 + j] + b0n, xn1 = W[320 + j] + b0n;
  const float bd0 = Bd[0], bd1 = Bd[1];

  float h = 0.0f;
  hsh[j] = 0.0f;
  float logP = 0.0f;
  float xz = b0z, xr = b0r, xn = b0n;   // t=0: x=0 -> xm = b[0]
  __syncthreads();

  for (int t = 0; t < NSTEP; ++t) {
    // hm = h@U (k-ascending f32 FMA from 0) then + b[1]
    float hz = 0.0f, hr = 0.0f, hn = 0.0f;
#pragma unroll
    for (int i0 = 0; i0 < HID; i0 += 4) {
      const float4 hb = *(const float4*)&hsh[i0];
      hz = __builtin_fmaf(hb.x, Uz[i0+0], hz); hr = __builtin_fmaf(hb.x, Ur[i0+0], hr); hn = __builtin_fmaf(hb.x, Un[i0+0], hn);
      hz = __builtin_fmaf(hb.y, Uz[i0+1], hz); hr = __builtin_fmaf(hb.y, Ur[i0+1], hr); hn = __builtin_fmaf(hb.y, Un[i0+1], hn);
      hz = __builtin_fmaf(hb.z, Uz[i0+2], hz); hr = __builtin_fmaf(hb.z, Ur[i0+2], hr); hn = __builtin_fmaf(hb.z, Un[i0+2], hn);
      hz = __builtin_fmaf(hb.w, Uz[i0+3], hz); hr = __builtin_fmaf(hb.w, Ur[i0+3], hr); hn = __builtin_fmaf(hb.w, Un[i0+3], hn);
    }
    hz = hz + b1z; hr = hr + b1r; hn = hn + b1n;

    // gates, naive np translit: 1/(1+exp(-x)), all f32 steps, no contraction
    const float az = xz + hz;
    const float ar = xr + hr;
    const float z  = 1.0f / (1.0f + cr_expf(-az));
    const float r  = 1.0f / (1.0f + cr_expf(-ar));
    const float hh = cr_tanhf(xn + (r * hn));
    h = (z * h) + ((1.0f - z) * hh);
    hsh[j] = h;   // single wave: LDS ops in program order

    // dense logits: h@Wd (k-ascending FMA from 0) + bd, redundantly uniform
    // per lane (uniform LDS reads broadcast; decisions wave-uniform)
    float p0 = 0.0f, p1 = 0.0f;
#pragma unroll
    for (int k0i = 0; k0i < HID; k0i += 4) {
      const float4 hb = *(const float4*)&hsh[k0i];
      const float4 w01 = *(const float4*)&wdsh[2*k0i];
      const float4 w23 = *(const float4*)&wdsh[2*k0i + 4];
      p0 = __builtin_fmaf(hb.x, w01.x, p0); p1 = __builtin_fmaf(hb.x, w01.y, p1);
      p0 = __builtin_fmaf(hb.y, w01.z, p0); p1 = __builtin_fmaf(hb.y, w01.w, p1);
      p0 = __builtin_fmaf(hb.z, w23.x, p0); p1 = __builtin_fmaf(hb.z, w23.y, p1);
      p0 = __builtin_fmaf(hb.w, w23.z, p0); p1 = __builtin_fmaf(hb.w, w23.w, p1);
    }
    const float l0 = p0 + bd0, l1 = p1 + bd1;

    // softmax (exp(x-max)/sum), log(EPS+p), all f32 steps
    const float mx = fmaxf(l0, l1);
    const float e0 = cr_expf(l0 - mx), e1 = cr_expf(l1 - mx);
    const float se = e0 + e1;
    const float lp0 = cr_logf(1e-10f + (e0 / se));
    const float lp1 = cr_logf(1e-10f + (e1 / se));

    const float g0 = gsh[2*t], g1 = gsh[2*t + 1];
    const int smp = (lp1 + g1) > (lp0 + g0) ? 1 : 0;   // np.argmax: first on tie
    logP = logP + (smp ? lp1 : lp0);
    if (j == 0) out[s * NSTEP + t] = smp ? 1.0f : 0.0f;
    xz = smp ? xz1 : xz0;
    xr = smp ? xr1 : xr0;
    xn = smp ? xn1 : xn0;
  }
  if (j == 0) out[NSAMP * NSTEP + s] = logP;
}

extern "C" void kernel_launch(void* const* d_in, const int* in_sizes, int n_in,
                              void* d_out, int out_size, void* d_ws, size_t ws_size,
                              hipStream_t stream) {
  // inputs (setup_inputs order): nsamples(1), W(2x192), U(64x192), b(2x192),
  // Wd(64x2), bd(2) — float32
  const float* W  = (const float*)d_in[1];
  const float* U  = (const float*)d_in[2];
  const float* B  = (const float*)d_in[3];
  const float* Wd = (const float*)d_in[4];
  const float* Bd = (const float*)d_in[5];
  vmc_kernel<<<dim3(NSAMP), dim3(HID), 0, stream>>>(W, U, B, Wd, Bd, (float*)d_out);
}

// Round 7
// 1783.267 us; speedup vs baseline: 1.0223x; 1.0223x over previous
//
#include <hip/hip_runtime.h>
#include <cstdint>
#include <math.h>

// GREEN r6 (1823 us): PRNG = partitionable threefry (split key_t = tf((0,42),(0,t));
// bits = o0^o1 of tf(key_t,(0,2s+c))); f32 in/out; out = [4096*144 samples][4096 logP].
// r6 post-mortem: VGPR=144 -> U arrays spilled to scratch (promote-alloca won't
// vectorize 64-elem arrays); ~49KB/wave/step re-read from L2 + cr_* f64-emulated
// transcendentals = the 1823 us. Decisions proven arithmetic-robust (r2/r3/r4:
// three arithmetics, bit-identical outcomes), so native f32 libm is safe.
// This round: U in 12 named ext_vector(16) SSA values (unspillable), 4 chains
// per wave (1024 blocks), native expf/logf/tanhf + v_rcp, dense h@Wd kept in
// r6's exact sequential k-ascending order (butterfly reserved as next experiment).

#define NSAMP 4096
#define NSTEP 144
#define HID 64
#define CPB 4            // chains per block (one wave)

typedef float v16f __attribute__((ext_vector_type(16)));

// ---- JAX threefry2x32 (20 rounds, key-inject every 4) ----
__device__ __forceinline__ void threefry2x32(uint32_t k0, uint32_t k1,
                                             uint32_t x0, uint32_t x1,
                                             uint32_t& o0, uint32_t& o1) {
  const uint32_t ks0 = k0, ks1 = k1, ks2 = k0 ^ k1 ^ 0x1BD11BDAu;
  x0 += ks0; x1 += ks1;
#define TF_ROUND(d) { x0 += x1; x1 = (x1 << (d)) | (x1 >> (32 - (d))); x1 ^= x0; }
  TF_ROUND(13) TF_ROUND(15) TF_ROUND(26) TF_ROUND(6)
  x0 += ks1; x1 += ks2 + 1u;
  TF_ROUND(17) TF_ROUND(29) TF_ROUND(16) TF_ROUND(24)
  x0 += ks2; x1 += ks0 + 2u;
  TF_ROUND(13) TF_ROUND(15) TF_ROUND(26) TF_ROUND(6)
  x0 += ks0; x1 += ks1 + 3u;
  TF_ROUND(17) TF_ROUND(29) TF_ROUND(16) TF_ROUND(24)
  x0 += ks1; x1 += ks2 + 4u;
  TF_ROUND(13) TF_ROUND(15) TF_ROUND(26) TF_ROUND(6)
  x0 += ks2; x1 += ks0 + 5u;
#undef TF_ROUND
  o0 = x0; o1 = x1;
}

__global__ __launch_bounds__(64, 1) void vmc_kernel(
    const float* __restrict__ W, const float* __restrict__ U,
    const float* __restrict__ B, const float* __restrict__ Wd,
    const float* __restrict__ Bd, float* __restrict__ out) {
#pragma clang fp contract(off)
  const int j = threadIdx.x;           // hidden unit owned by this lane
  const int s_base = blockIdx.x * CPB; // first of 4 chains in this block

  __shared__ __align__(16) float4 hsh4[HID];       // h[unit] = {c0,c1,c2,c3}
  __shared__ __align__(16) float wdsh[2 * HID];    // Wd row-major (64,2)
  __shared__ uint2 kkeys[NSTEP];
  __shared__ float gsh[CPB * 2 * NSTEP];           // gumbels [c][2t+cat]

  // --- per-step keys: key_t = threefry((0,42),(0,t)) ---
#pragma unroll
  for (int k = 0; k < 3; ++k) {
    const int t = j + 64 * k;
    if (t < NSTEP) {
      uint32_t o0, o1;
      threefry2x32(0u, 42u, 0u, (uint32_t)t, o0, o1);
      kkeys[t].x = o0; kkeys[t].y = o1;
    }
  }
  wdsh[j] = Wd[j]; wdsh[j + 64] = Wd[j + 64];
  hsh4[j] = float4{0.0f, 0.0f, 0.0f, 0.0f};
  __syncthreads();

  // --- gumbels for 4 chains x 288 draws: bits = o0^o1 of tf(key_t,(0,2s+cat)) ---
#pragma unroll
  for (int k = 0; k < 18; ++k) {
    const int id = j + 64 * k;              // 0..1151 = c*288 + idx
    const int c = id / 288;
    const int idx = id - c * 288;
    const uint2 kt = kkeys[idx >> 1];
    const uint32_t i = 2u * (uint32_t)(s_base + c) + (uint32_t)(idx & 1);
    uint32_t o0, o1;
    threefry2x32(kt.x, kt.y, 0u, i, o0, o1);
    const uint32_t bits = o0 ^ o1;
    union { uint32_t u; float f; } cv; cv.u = (bits >> 9) | 0x3F800000u;
    float uf = cv.f - 1.0f;
    uf = fmaxf(uf, 1.17549435e-38f);
    const float inner = logf(uf);
    gsh[id] = -logf(-inner);
  }
  __syncthreads();

  // --- U columns for unit j, register-resident as named SSA vectors ---
  v16f uz0, uz1, uz2, uz3, ur0, ur1, ur2, ur3, un0, un1, un2, un3;
#define LOADB(v, r, off) \
  { _Pragma("unroll") for (int e = 0; e < 16; ++e) v[e] = U[((r)*16 + e)*192 + (off) + j]; }
  LOADB(uz0, 0, 0)  LOADB(uz1, 1, 0)  LOADB(uz2, 2, 0)  LOADB(uz3, 3, 0)
  LOADB(ur0, 0, 64) LOADB(ur1, 1, 64) LOADB(ur2, 2, 64) LOADB(ur3, 3, 64)
  LOADB(un0, 0, 128) LOADB(un1, 1, 128) LOADB(un2, 2, 128) LOADB(un3, 3, 128)
#undef LOADB

  const float b1z = B[192 + j], b1r = B[256 + j], b1n = B[320 + j];
  const float b0z = B[j],       b0r = B[64 + j],  b0n = B[128 + j];
  const float cxz0 = W[j]        + b0z, cxz1 = W[192 + j] + b0z;
  const float cxr0 = W[64 + j]   + b0r, cxr1 = W[256 + j] + b0r;
  const float cxn0 = W[128 + j]  + b0n, cxn1 = W[320 + j] + b0n;
  const float bd0 = Bd[0], bd1 = Bd[1];

#define FOR4(M) M(0) M(1) M(2) M(3)
#define DECL(c) float h##c = 0.0f, logP##c = 0.0f, xz##c = b0z, xr##c = b0r, xn##c = b0n;
  FOR4(DECL)
#undef DECL

  for (int t = 0; t < NSTEP; ++t) {
    // ---- hm = h@U (k-ascending f32 FMA from 0), 4 chains at once ----
    float hz0 = 0.f, hz1 = 0.f, hz2 = 0.f, hz3 = 0.f;
    float hr0 = 0.f, hr1 = 0.f, hr2 = 0.f, hr3 = 0.f;
    float hn0 = 0.f, hn1 = 0.f, hn2 = 0.f, hn3 = 0.f;
#define DOTB(uzv, urv, unv, base) \
    { _Pragma("unroll") for (int e = 0; e < 16; ++e) { \
        const float4 hb = hsh4[(base) + e]; \
        hz0 = __builtin_fmaf(hb.x, uzv[e], hz0); \
        hz1 = __builtin_fmaf(hb.y, uzv[e], hz1); \
        hz2 = __builtin_fmaf(hb.z, uzv[e], hz2); \
        hz3 = __builtin_fmaf(hb.w, uzv[e], hz3); \
        hr0 = __builtin_fmaf(hb.x, urv[e], hr0); \
        hr1 = __builtin_fmaf(hb.y, urv[e], hr1); \
        hr2 = __builtin_fmaf(hb.z, urv[e], hr2); \
        hr3 = __builtin_fmaf(hb.w, urv[e], hr3); \
        hn0 = __builtin_fmaf(hb.x, unv[e], hn0); \
        hn1 = __builtin_fmaf(hb.y, unv[e], hn1); \
        hn2 = __builtin_fmaf(hb.z, unv[e], hn2); \
        hn3 = __builtin_fmaf(hb.w, unv[e], hn3); } }
    DOTB(uz0, ur0, un0, 0)
    DOTB(uz1, ur1, un1, 16)
    DOTB(uz2, ur2, un2, 32)
    DOTB(uz3, ur3, un3, 48)
#undef DOTB

    // ---- gates (native f32: expf + v_rcp, tanhf), r6 expression order ----
#define GATES(c) \
    { const float tz = hz##c + b1z, tr = hr##c + b1r, tn = hn##c + b1n; \
      const float az = xz##c + tz, ar = xr##c + tr; \
      const float zz = __builtin_amdgcn_rcpf(1.0f + expf(-az)); \
      const float rr = __builtin_amdgcn_rcpf(1.0f + expf(-ar)); \
      const float hhv = tanhf(xn##c + (rr * tn)); \
      h##c = (zz * h##c) + ((1.0f - zz) * hhv); }
    FOR4(GATES)
#undef GATES

    hsh4[j] = float4{h0, h1, h2, h3};   // single wave: LDS ops program-ordered

    // ---- dense h@Wd: exact r6 rounding (k-ascending sequential FMA),
    // computed redundantly per lane from uniform LDS broadcasts ----
    float pa0 = 0.f, pa1 = 0.f, pa2 = 0.f, pa3 = 0.f;   // logit 0 per chain
    float pb0 = 0.f, pb1 = 0.f, pb2 = 0.f, pb3 = 0.f;   // logit 1 per chain
#pragma unroll
    for (int i0 = 0; i0 < HID; i0 += 2) {
      const float4 ha = hsh4[i0];
      const float4 hb = hsh4[i0 + 1];
      const float4 w = *((const float4*)wdsh + (i0 >> 1)); // wd[i0].{0,1}, wd[i0+1].{0,1}
      pa0 = __builtin_fmaf(ha.x, w.x, pa0); pb0 = __builtin_fmaf(ha.x, w.y, pb0);
      pa1 = __builtin_fmaf(ha.y, w.x, pa1); pb1 = __builtin_fmaf(ha.y, w.y, pb1);
      pa2 = __builtin_fmaf(ha.z, w.x, pa2); pb2 = __builtin_fmaf(ha.z, w.y, pb2);
      pa3 = __builtin_fmaf(ha.w, w.x, pa3); pb3 = __builtin_fmaf(ha.w, w.y, pb3);
      pa0 = __builtin_fmaf(hb.x, w.z, pa0); pb0 = __builtin_fmaf(hb.x, w.w, pb0);
      pa1 = __builtin_fmaf(hb.y, w.z, pa1); pb1 = __builtin_fmaf(hb.y, w.w, pb1);
      pa2 = __builtin_fmaf(hb.z, w.z, pa2); pb2 = __builtin_fmaf(hb.z, w.w, pb2);
      pa3 = __builtin_fmaf(hb.w, w.z, pa3); pb3 = __builtin_fmaf(hb.w, w.w, pb3);
    }

    // ---- softmax + gumbel argmax + logP, native f32 ----
    int smp0, smp1, smp2, smp3;
#define SAMPLE(c) \
    { const float l0 = pa##c + bd0, l1 = pb##c + bd1; \
      const float mxv = fmaxf(l0, l1); \
      const float e0 = expf(l0 - mxv), e1 = expf(l1 - mxv); \
      const float rs = __builtin_amdgcn_rcpf(e0 + e1); \
      const float lp0 = logf(1e-10f + (e0 * rs)); \
      const float lp1 = logf(1e-10f + (e1 * rs)); \
      const float g0 = gsh[(c)*2*NSTEP + 2*t], g1 = gsh[(c)*2*NSTEP + 2*t + 1]; \
      const int sm = (lp1 + g1) > (lp0 + g0); \
      logP##c = logP##c + (sm ? lp1 : lp0); \
      smp##c = sm; \
      xz##c = sm ? cxz1 : cxz0; \
      xr##c = sm ? cxr1 : cxr0; \
      xn##c = sm ? cxn1 : cxn0; }
    FOR4(SAMPLE)
#undef SAMPLE

    if (j == 0) {
      out[(s_base + 0) * NSTEP + t] = smp0 ? 1.0f : 0.0f;
      out[(s_base + 1) * NSTEP + t] = smp1 ? 1.0f : 0.0f;
      out[(s_base + 2) * NSTEP + t] = smp2 ? 1.0f : 0.0f;
      out[(s_base + 3) * NSTEP + t] = smp3 ? 1.0f : 0.0f;
    }
  }

  if (j == 0) {
    *(float4*)&out[NSAMP * NSTEP + s_base] = float4{logP0, logP1, logP2, logP3};
  }
#undef FOR4
}

extern "C" void kernel_launch(void* const* d_in, const int* in_sizes, int n_in,
                              void* d_out, int out_size, void* d_ws, size_t ws_size,
                              hipStream_t stream) {
  // inputs (setup_inputs order): nsamples(1), W(2x192), U(64x192), b(2x192),
  // Wd(64x2), bd(2) — float32
  const float* W  = (const float*)d_in[1];
  const float* U  = (const float*)d_in[2];
  const float* B  = (const float*)d_in[3];
  const float* Wd = (const float*)d_in[4];
  const float* Bd = (const float*)d_in[5];
  vmc_kernel<<<dim3(NSAMP / CPB), dim3(HID), 0, stream>>>(W, U, B, Wd, Bd, (float*)d_out);
}